// Round 2
// baseline (204.967 us; speedup 1.0000x reference)
//
#include <hip/hip_runtime.h>

// N=1e6 points x 32 fp32 (16 outer dims + 16 inner dims), 64 outer centers,
// 8 inner centers each. out[p] = argmin_inner + 8*argmin_outer (int32).
constexpr int D = 16;
constexpr int NC = 64;
constexpr int NCPC = 8;
constexpr int OSTRIDE = NCPC * D + 4;   // 132 floats: start bank = (4*o)%32, 16B aligned
constexpr int NPT = 4;                  // points per thread (register-blocked)
constexpr int BLOCK = 256;

__global__ __launch_bounds__(BLOCK, 4)
void cluster_kernel(const float* __restrict__ x,
                    const float* __restrict__ co,
                    const float* __restrict__ ci,
                    int* __restrict__ out, int n)
{
    // LDS: inner centers (divergent gather) + precomputed norms. 36.3 KB -> 4 blocks/CU.
    __shared__ __align__(16) float s_ci[NC * OSTRIDE];
    __shared__ __align__(16) float s_onorm[NC];
    __shared__ float s_inorm[NC * 9];           // [o][k] stride 9 to spread banks

    const int t = threadIdx.x;

    // ---- Stage inner centers (2048 float4) into LDS, coalesced ----
    const float4* ci4 = (const float4*)ci;
#pragma unroll
    for (int i = 0; i < 8; ++i) {
        int idx = t + i * BLOCK;        // 0..2047
        int o = idx >> 5;               // 32 float4 per outer cluster
        int f = idx & 31;
        *(float4*)&s_ci[o * OSTRIDE + f * 4] = ci4[idx];
    }
    // ---- 576 norms once per block ----
    for (int i = t; i < NC + NC * NCPC; i += BLOCK) {
        const float* src = (i < NC) ? (co + i * D) : (ci + (size_t)(i - NC) * D);
        float s = 0.f;
#pragma unroll
        for (int k = 0; k < D; ++k) s = fmaf(src[k], src[k], s);
        if (i < NC) s_onorm[i] = s;
        else { int ii = i - NC; s_inorm[(ii >> 3) * 9 + (ii & 7)] = s; }
    }
    __syncthreads();

    const int base = blockIdx.x * (BLOCK * NPT) + t;

    // Clamp out-of-range points to n-1 (compute garbage, store guarded) —
    // avoids divergent loads, keeps one uniform code path.
    int p[NPT];
    bool valid[NPT];
#pragma unroll
    for (int pt = 0; pt < NPT; ++pt) {
        int pp = base + pt * BLOCK;
        valid[pt] = pp < n;
        p[pt] = valid[pt] ? pp : (n - 1);
    }

    // ---- Phase 1: outer argmin, 4 points blocked so each center load is
    //      amortized 4x. Center indices are compile-time-uniform -> the
    //      compiler can emit s_load (constant cache), zero VMEM cost. ----
    float x1[NPT][D];
#pragma unroll
    for (int pt = 0; pt < NPT; ++pt) {
        const float4* xp = (const float4*)(x + (size_t)p[pt] * 32);
        float4 a = xp[0], b = xp[1], c = xp[2], d = xp[3];
        x1[pt][0]=a.x;  x1[pt][1]=a.y;  x1[pt][2]=a.z;  x1[pt][3]=a.w;
        x1[pt][4]=b.x;  x1[pt][5]=b.y;  x1[pt][6]=b.z;  x1[pt][7]=b.w;
        x1[pt][8]=c.x;  x1[pt][9]=c.y;  x1[pt][10]=c.z; x1[pt][11]=c.w;
        x1[pt][12]=d.x; x1[pt][13]=d.y; x1[pt][14]=d.z; x1[pt][15]=d.w;
    }

    float bestd[NPT]; int bo[NPT];
#pragma unroll
    for (int pt = 0; pt < NPT; ++pt) { bestd[pt] = 3.4e38f; bo[pt] = 0; }

#pragma unroll 2                       // bound register pressure; 32 s_loads in flight
    for (int j = 0; j < NC; ++j) {
        float cj[D];
#pragma unroll
        for (int k = 0; k < D; ++k) cj[k] = co[j * D + k];   // uniform address
        float nrm = s_onorm[j];                               // broadcast ds_read
#pragma unroll
        for (int pt = 0; pt < NPT; ++pt) {
            float dot = 0.f;
#pragma unroll
            for (int k = 0; k < D; ++k) dot = fmaf(x1[pt][k], cj[k], dot);
            float dd = fmaf(-2.f, dot, nrm);
            if (dd < bestd[pt]) { bestd[pt] = dd; bo[pt] = j; }  // strict <: np.argmin ties
        }
    }

    // ---- Phase 2: inner argmin (LDS gather by per-lane bo). x2 loaded here;
    //      its cache lines were touched in phase 1 -> L2 hit. x1 regs dead. ----
#pragma unroll
    for (int pt = 0; pt < NPT; ++pt) {
        const float4* xp = (const float4*)(x + (size_t)p[pt] * 32);
        float4 a = xp[4], b = xp[5], c = xp[6], d = xp[7];
        float x2[D] = {a.x,a.y,a.z,a.w, b.x,b.y,b.z,b.w,
                       c.x,c.y,c.z,c.w, d.x,d.y,d.z,d.w};
        const float* cb = s_ci + bo[pt] * OSTRIDE;
        const float* nb = s_inorm + bo[pt] * 9;
        float bd = 3.4e38f; int bk = 0;
#pragma unroll
        for (int k = 0; k < NCPC; ++k) {
            float4 c0 = *(const float4*)&cb[k * D + 0];
            float4 c1 = *(const float4*)&cb[k * D + 4];
            float4 c2 = *(const float4*)&cb[k * D + 8];
            float4 c3 = *(const float4*)&cb[k * D + 12];
            float dot = 0.f;
            dot = fmaf(x2[0],  c0.x, dot); dot = fmaf(x2[1],  c0.y, dot);
            dot = fmaf(x2[2],  c0.z, dot); dot = fmaf(x2[3],  c0.w, dot);
            dot = fmaf(x2[4],  c1.x, dot); dot = fmaf(x2[5],  c1.y, dot);
            dot = fmaf(x2[6],  c1.z, dot); dot = fmaf(x2[7],  c1.w, dot);
            dot = fmaf(x2[8],  c2.x, dot); dot = fmaf(x2[9],  c2.y, dot);
            dot = fmaf(x2[10], c2.z, dot); dot = fmaf(x2[11], c2.w, dot);
            dot = fmaf(x2[12], c3.x, dot); dot = fmaf(x2[13], c3.y, dot);
            dot = fmaf(x2[14], c3.z, dot); dot = fmaf(x2[15], c3.w, dot);
            float dd = fmaf(-2.f, dot, nb[k]);
            if (dd < bd) { bd = dd; bk = k; }
        }
        if (valid[pt]) out[p[pt]] = bo[pt] * NCPC + bk;
    }
}

extern "C" void kernel_launch(void* const* d_in, const int* in_sizes, int n_in,
                              void* d_out, int out_size, void* d_ws, size_t ws_size,
                              hipStream_t stream) {
    const float* x  = (const float*)d_in[0];   // (N, 32) fp32
    const float* co = (const float*)d_in[1];   // (64, 16) fp32
    const float* ci = (const float*)d_in[2];   // (64, 8, 16) fp32
    int* out = (int*)d_out;                    // (N,) int32
    int n = in_sizes[0] / 32;
    int blocks = (n + BLOCK * NPT - 1) / (BLOCK * NPT);
    cluster_kernel<<<blocks, BLOCK, 0, stream>>>(x, co, ci, out, n);
}

// Round 3
// 200.095 us; speedup vs baseline: 1.0243x; 1.0243x over previous
//
#include <hip/hip_runtime.h>

// N=1e6 points x 32 fp32 (16 outer + 16 inner dims), 64 outer centers, 8 inner each.
// out[p] = argmin_inner + 8*argmin_outer (int32).
constexpr int D = 16;
constexpr int NC = 64;
constexpr int NCPC = 8;
constexpr int OSTRIDE = NCPC * D + 4;   // 132 floats: stagger start bank by outer idx, 16B aligned
constexpr int NPT = 2;                  // points per thread (kept low so x stays in VGPRs)
constexpr int BLOCK = 256;

__device__ __forceinline__ float lane_bcast(float v, int lane) {
    // v_readlane_b32: broadcast lane's value through an SGPR. 1 VALU issue, no LDS pipe.
    return __int_as_float(__builtin_amdgcn_readlane(__float_as_int(v), lane));
}

__global__ __launch_bounds__(BLOCK, 4)
void cluster_kernel(const float* __restrict__ x,
                    const float* __restrict__ co,
                    const float* __restrict__ ci,
                    int* __restrict__ out, int n)
{
    // LDS only for phase 2 (divergent inner-center gather) + norm staging. 36.3 KB -> 4 blocks/CU.
    __shared__ __align__(16) float s_ci[NC * OSTRIDE];
    __shared__ float s_onorm[NC];
    __shared__ float s_inorm[NC * 9];           // [o][k] stride 9 to spread banks

    const int t = threadIdx.x;

    // ---- Stage inner centers (2048 float4) into LDS, coalesced ----
    const float4* ci4 = (const float4*)ci;
#pragma unroll
    for (int i = 0; i < 8; ++i) {
        int idx = t + i * BLOCK;
        int o = idx >> 5;
        int f = idx & 31;
        *(float4*)&s_ci[o * OSTRIDE + f * 4] = ci4[idx];
    }
    // ---- 576 norms once per block ----
    for (int i = t; i < NC + NC * NCPC; i += BLOCK) {
        const float* src = (i < NC) ? (co + i * D) : (ci + (size_t)(i - NC) * D);
        float s = 0.f;
#pragma unroll
        for (int k = 0; k < D; ++k) s = fmaf(src[k], src[k], s);
        if (i < NC) s_onorm[i] = s;
        else { int ii = i - NC; s_inorm[(ii >> 3) * 9 + (ii & 7)] = s; }
    }
    __syncthreads();

    // Per-lane copy of the 64 outer norms: lane l holds ||c_l||^2.
    // Hot loop broadcasts lane j via v_readlane -> NO LDS in the j-loop.
    float mynorm = s_onorm[t & 63];

    const int base = blockIdx.x * (BLOCK * NPT) + t;
    int p[NPT]; bool valid[NPT];
#pragma unroll
    for (int pt = 0; pt < NPT; ++pt) {
        int pp = base + pt * BLOCK;
        valid[pt] = pp < n;
        p[pt] = valid[pt] ? pp : (n - 1);   // clamp: uniform code path, store guarded
    }

    // ---- Load both points fully (x1 + x2) up front: one vmcnt burst, x2's HBM
    //      fetch overlaps phase-1 compute. 64 floats -> fits (NPT=2). ----
    float x1[NPT][D], x2[NPT][D];
#pragma unroll
    for (int pt = 0; pt < NPT; ++pt) {
        const float4* xp = (const float4*)(x + (size_t)p[pt] * 32);
        float4 a = xp[0], b = xp[1], c = xp[2], d = xp[3];
        float4 e = xp[4], f = xp[5], g = xp[6], h = xp[7];
        x1[pt][0]=a.x;  x1[pt][1]=a.y;  x1[pt][2]=a.z;  x1[pt][3]=a.w;
        x1[pt][4]=b.x;  x1[pt][5]=b.y;  x1[pt][6]=b.z;  x1[pt][7]=b.w;
        x1[pt][8]=c.x;  x1[pt][9]=c.y;  x1[pt][10]=c.z; x1[pt][11]=c.w;
        x1[pt][12]=d.x; x1[pt][13]=d.y; x1[pt][14]=d.z; x1[pt][15]=d.w;
        x2[pt][0]=e.x;  x2[pt][1]=e.y;  x2[pt][2]=e.z;  x2[pt][3]=e.w;
        x2[pt][4]=f.x;  x2[pt][5]=f.y;  x2[pt][6]=f.z;  x2[pt][7]=f.w;
        x2[pt][8]=g.x;  x2[pt][9]=g.y;  x2[pt][10]=g.z; x2[pt][11]=g.w;
        x2[pt][12]=h.x; x2[pt][13]=h.y; x2[pt][14]=h.z; x2[pt][15]=h.w;
    }

    float bestd[NPT]; int bo[NPT];
#pragma unroll
    for (int pt = 0; pt < NPT; ++pt) { bestd[pt] = 3.4e38f; bo[pt] = 0; }

    // ---- Phase 1: outer argmin. Uniform center address -> s_load (scalar pipe,
    //      zero VALU cost). Explicit cur/nxt software pipeline: next center's
    //      s_load_dwordx16 is in flight during this center's FMAs. ----
    float cur[D];
#pragma unroll
    for (int k = 0; k < D; ++k) cur[k] = co[k];

#pragma unroll 2
    for (int j = 0; j < NC; ++j) {
        float nxt[D];
        int jn = (j < NC - 1) ? (j + 1) : j;
#pragma unroll
        for (int k = 0; k < D; ++k) nxt[k] = co[jn * D + k];   // uniform -> s_load, independent of compute
        float nrm = lane_bcast(mynorm, j);
#pragma unroll
        for (int pt = 0; pt < NPT; ++pt) {
            float dot = 0.f;
#pragma unroll
            for (int k = 0; k < D; ++k) dot = fmaf(x1[pt][k], cur[k], dot);  // same chain order as R2 (tie-safe)
            float dd = fmaf(-2.f, dot, nrm);
            if (dd < bestd[pt]) { bestd[pt] = dd; bo[pt] = j; }  // strict <: np.argmin first-index
        }
#pragma unroll
        for (int k = 0; k < D; ++k) cur[k] = nxt[k];            // s_mov rotate (scalar pipe)
    }

    // ---- Phase 2: inner argmin (LDS gather by per-lane bo), x2 already in regs ----
#pragma unroll
    for (int pt = 0; pt < NPT; ++pt) {
        const float* cb = s_ci + bo[pt] * OSTRIDE;
        const float* nb = s_inorm + bo[pt] * 9;
        float bd = 3.4e38f; int bk = 0;
#pragma unroll
        for (int k = 0; k < NCPC; ++k) {
            float4 c0 = *(const float4*)&cb[k * D + 0];
            float4 c1 = *(const float4*)&cb[k * D + 4];
            float4 c2 = *(const float4*)&cb[k * D + 8];
            float4 c3 = *(const float4*)&cb[k * D + 12];
            float dot = 0.f;
            dot = fmaf(x2[pt][0],  c0.x, dot); dot = fmaf(x2[pt][1],  c0.y, dot);
            dot = fmaf(x2[pt][2],  c0.z, dot); dot = fmaf(x2[pt][3],  c0.w, dot);
            dot = fmaf(x2[pt][4],  c1.x, dot); dot = fmaf(x2[pt][5],  c1.y, dot);
            dot = fmaf(x2[pt][6],  c1.z, dot); dot = fmaf(x2[pt][7],  c1.w, dot);
            dot = fmaf(x2[pt][8],  c2.x, dot); dot = fmaf(x2[pt][9],  c2.y, dot);
            dot = fmaf(x2[pt][10], c2.z, dot); dot = fmaf(x2[pt][11], c2.w, dot);
            dot = fmaf(x2[pt][12], c3.x, dot); dot = fmaf(x2[pt][13], c3.y, dot);
            dot = fmaf(x2[pt][14], c3.z, dot); dot = fmaf(x2[pt][15], c3.w, dot);
            float dd = fmaf(-2.f, dot, nb[k]);
            if (dd < bd) { bd = dd; bk = k; }
        }
        if (valid[pt]) out[p[pt]] = bo[pt] * NCPC + bk;
    }
}

extern "C" void kernel_launch(void* const* d_in, const int* in_sizes, int n_in,
                              void* d_out, int out_size, void* d_ws, size_t ws_size,
                              hipStream_t stream) {
    const float* x  = (const float*)d_in[0];   // (N, 32) fp32
    const float* co = (const float*)d_in[1];   // (64, 16) fp32
    const float* ci = (const float*)d_in[2];   // (64, 8, 16) fp32
    int* out = (int*)d_out;                    // (N,) int32
    int n = in_sizes[0] / 32;
    int blocks = (n + BLOCK * NPT - 1) / (BLOCK * NPT);
    cluster_kernel<<<blocks, BLOCK, 0, stream>>>(x, co, ci, out, n);
}